// Round 16
// baseline (152.355 us; speedup 1.0000x reference)
//
#include <hip/hip_runtime.h>

// Holt-Winters, 32768 windows x 511 steps, 1 thread/window, 1 wave/block.
// R9 post-mortem: register-pipelined divergent loads plateau at ~34us --
// VMEM request flood (64 lines per wave-load, ~8K requests/wave) saturates
// the memory queue; deeper ILP can't issue past it. This version stages x
// through LDS with COALESCED global loads (~8x fewer transactions),
// SBAR-pinned prefetch (superblock s+1 issued before s's 96-step compute),
// ds_read_b128 row reads at stride 100 (16B-aligned, bank-balanced),
// chunk-ahead LDS reads. S[24] in registers (96%24==0 -> static indices).

#define F_WINDOW 512
#define SEASONP  24
#define HORIZON  12
#define LSTRIDE  100     // floats; 400B row stride: 16B-aligned, 8 words/bank

#define SBAR() __builtin_amdgcn_sched_barrier(0)

// One smoothing step. si MUST be a compile-time constant.
// u-form for bn: bn = (1-ab)*b - ab*L + ab*(xi-Sv) (no dependence on Ln).
#define HW_STEP(xi, si) do {                       \
    const float Sv  = S[si];                       \
    const float d   = (xi) - Sv;                   \
    const float ad  = alpha * d;                   \
    const float s_  = L + b;                       \
    const float Ln  = fmaf(oma, s_, ad);           \
    const float abd = beta * ad;                   \
    const float tb  = fmaf(omab, b, abd);          \
    const float bn  = fmaf(ab, -L, tb);            \
    const float e   = (xi) - Ln;                   \
    const float gs  = omg * Sv;                    \
    S[si] = fmaf(gamma, e, gs);                    \
    L = Ln; b = bn;                                \
} while (0)

// 24 steps from six float4; entry step index i satisfies i % 24 == 4.
#define HW_BLOCK24(v0, v1, v2, v3, v4, v5) do {                                  \
    HW_STEP(v0.x,  4); HW_STEP(v0.y,  5); HW_STEP(v0.z,  6); HW_STEP(v0.w,  7); \
    HW_STEP(v1.x,  8); HW_STEP(v1.y,  9); HW_STEP(v1.z, 10); HW_STEP(v1.w, 11); \
    HW_STEP(v2.x, 12); HW_STEP(v2.y, 13); HW_STEP(v2.z, 14); HW_STEP(v2.w, 15); \
    HW_STEP(v3.x, 16); HW_STEP(v3.y, 17); HW_STEP(v3.z, 18); HW_STEP(v3.w, 19); \
    HW_STEP(v4.x, 20); HW_STEP(v4.y, 21); HW_STEP(v4.z, 22); HW_STEP(v4.w, 23); \
    HW_STEP(v5.x,  0); HW_STEP(v5.y,  1); HW_STEP(v5.z,  2); HW_STEP(v5.w,  3); \
} while (0)

// Coalesced issue of one superblock (64 rows x 96 floats) into stg[24].
// Flat float4 index g = j*64 + t -> row r = g/24, f4-col c = g%24: each
// instruction covers ~3 contiguous 384B row segments (vs 64 lines naive).
#define ISSUE_LOADS(sb) do {                                      \
    const float* gp = xblk + 4 + 96 * (sb);                       \
    int r = r0, c = c0;                                           \
    _Pragma("unroll")                                             \
    for (int j = 0; j < 24; ++j) {                                \
        stg[j] = *(const float4*)(gp + r * F_WINDOW + 4 * c);     \
        c += 16; r += 2;                                          \
        if (c >= 24) { c -= 24; r += 1; }                         \
    }                                                             \
} while (0)

// Scatter stg[] into an LDS buffer (ds_write_b128, 16B-aligned).
#define WRITE_LDS(buf) do {                                       \
    int r = r0, c = c0;                                           \
    _Pragma("unroll")                                             \
    for (int j = 0; j < 24; ++j) {                                \
        *(float4*)((buf) + r * LSTRIDE + 4 * c) = stg[j];         \
        c += 16; r += 2;                                          \
        if (c >= 24) { c -= 24; r += 1; }                         \
    }                                                             \
} while (0)

// Six ds_read_b128 of chunk k (24 floats) of this thread's row.
#define READ6(Bn, k) do {                                         \
    Bn##0 = rowp[6*(k)+0]; Bn##1 = rowp[6*(k)+1];                 \
    Bn##2 = rowp[6*(k)+2]; Bn##3 = rowp[6*(k)+3];                 \
    Bn##4 = rowp[6*(k)+4]; Bn##5 = rowp[6*(k)+5];                 \
} while (0)

__global__ __launch_bounds__(64) void holtwinter_kernel(
    const float* __restrict__ x,
    const float* __restrict__ y,
    const float* __restrict__ init_L,
    const float* __restrict__ init_b,
    const float* __restrict__ init_S,
    const float* __restrict__ p_alpha,
    const float* __restrict__ p_beta,
    const float* __restrict__ p_gamma,
    float* __restrict__ out)
{
    __shared__ float lds[2][64 * LSTRIDE];   // 2 x 25.0 KB

    const int t = threadIdx.x;
    const int n = blockIdx.x * 64 + t;
    const int r0 = t / 24;
    const int c0 = t - r0 * 24;

    const float alpha = p_alpha[0];
    const float beta  = p_beta[0];
    const float gamma = p_gamma[0];
    const float oma   = 1.0f - alpha;
    const float ab    = alpha * beta;
    const float omab  = 1.0f - ab;
    const float omg   = 1.0f - gamma;

    const float* __restrict__ xblk = x + (size_t)blockIdx.x * 64 * F_WINDOW;
    const float* __restrict__ xr   = x + (size_t)n * F_WINDOW;

    // ---- scalar/per-thread loads FIRST (so prologue doesn't wait on
    //      the staging loads: vmcnt is FIFO), then staging for sb 0. ----
    const float4 P  = *(const float4*)(xr);        // i = 0..3 (x[0] unused)
    const float4 T  = *(const float4*)(xr + 508);  // tail i = 508..511
    const float  yv = y[n];
    const float  L0 = init_L[n];
    const float  b0 = init_b[n];
    float S[SEASONP];
    {
        const float4* iS4 = (const float4*)(init_S + (size_t)n * SEASONP);
        float4 s0 = iS4[0], s1 = iS4[1], s2 = iS4[2];
        float4 s3 = iS4[3], s4 = iS4[4], s5 = iS4[5];
        S[0]=s0.x;  S[1]=s0.y;  S[2]=s0.z;  S[3]=s0.w;
        S[4]=s1.x;  S[5]=s1.y;  S[6]=s1.z;  S[7]=s1.w;
        S[8]=s2.x;  S[9]=s2.y;  S[10]=s2.z; S[11]=s2.w;
        S[12]=s3.x; S[13]=s3.y; S[14]=s3.z; S[15]=s3.w;
        S[16]=s4.x; S[17]=s4.y; S[18]=s4.z; S[19]=s4.w;
        S[20]=s5.x; S[21]=s5.y; S[22]=s5.z; S[23]=s5.w;
    }

    float4 stg[24];
    float* bcur = lds[0];
    float* bnxt = lds[1];

    ISSUE_LOADS(0);        // superblock 0 (i = 4..99) in flight
    SBAR();

    float L = L0;
    float b = b0;

    // Prologue i = 1..3 (needs only the early scalar loads).
    HW_STEP(P.y, 1);
    HW_STEP(P.z, 2);
    HW_STEP(P.w, 3);
    SBAR();

    WRITE_LDS(bcur);       // waits staging loads, writes LDS
    __syncthreads();

    float4 R0, R1, R2, R3, R4, R5;
    float4 Q0, Q1, Q2, Q3, Q4, Q5;

    // Superblocks 0..3: compute 96 steps from LDS while s+1's global
    // loads fly; LDS chunk reads issued one 24-step block ahead.
    #pragma unroll 1
    for (int s = 0; s < 4; ++s) {
        ISSUE_LOADS(s + 1); SBAR();                 // ~2000 cyc to land
        const float4* rowp = (const float4*)(bcur + t * LSTRIDE);
        READ6(R, 0); READ6(Q, 1); SBAR();
        HW_BLOCK24(R0, R1, R2, R3, R4, R5); SBAR(); // chunk 0
        READ6(R, 2); SBAR();
        HW_BLOCK24(Q0, Q1, Q2, Q3, Q4, Q5); SBAR(); // chunk 1
        READ6(Q, 3); SBAR();
        HW_BLOCK24(R0, R1, R2, R3, R4, R5); SBAR(); // chunk 2
        HW_BLOCK24(Q0, Q1, Q2, Q3, Q4, Q5); SBAR(); // chunk 3
        WRITE_LDS(bnxt); SBAR();                    // staging long landed
        __syncthreads();
        float* tmp = bcur; bcur = bnxt; bnxt = tmp;
    }

    // Superblock 4 (i = 388..483): compute only.
    {
        const float4* rowp = (const float4*)(bcur + t * LSTRIDE);
        READ6(R, 0); READ6(Q, 1); SBAR();
        HW_BLOCK24(R0, R1, R2, R3, R4, R5); SBAR();
        READ6(R, 2); SBAR();
        HW_BLOCK24(Q0, Q1, Q2, Q3, Q4, Q5); SBAR();
        READ6(Q, 3); SBAR();
        HW_BLOCK24(R0, R1, R2, R3, R4, R5); SBAR();
        HW_BLOCK24(Q0, Q1, Q2, Q3, Q4, Q5);
    }

    // Tail: i = 484..507 direct (divergent but 6 instr, one-time), then
    // i = 508..511 from T. 484 % 24 == 4.
    {
        const float4 v0 = *(const float4*)(xr + 484);
        const float4 v1 = *(const float4*)(xr + 488);
        const float4 v2 = *(const float4*)(xr + 492);
        const float4 v3 = *(const float4*)(xr + 496);
        const float4 v4 = *(const float4*)(xr + 500);
        const float4 v5 = *(const float4*)(xr + 504);
        HW_BLOCK24(v0, v1, v2, v3, v4, v5);          // i = 484..507
        HW_STEP(T.x, 4); HW_STEP(T.y, 5);            // i = 508..511
        HW_STEP(T.z, 6); HW_STEP(T.w, 7);
    }

    // Forecast & loss term. s_idx = (511 + 12) % 24 = 19.
    const float f    = fmaf((float)HORIZON, b, L) * S[19];
    const float diff = f - yv;
    float val = diff * diff;

    // Wave (=block) reduction, one atomic per block.
    #pragma unroll
    for (int off = 32; off > 0; off >>= 1)
        val += __shfl_down(val, off);
    if (t == 0)
        atomicAdd(out, val);
}

extern "C" void kernel_launch(void* const* d_in, const int* in_sizes, int n_in,
                              void* d_out, int out_size, void* d_ws, size_t ws_size,
                              hipStream_t stream) {
    const float* x      = (const float*)d_in[0];
    const float* y      = (const float*)d_in[1];
    const float* init_L = (const float*)d_in[2];
    const float* init_b = (const float*)d_in[3];
    const float* init_S = (const float*)d_in[4];
    const float* alpha  = (const float*)d_in[5];
    const float* beta   = (const float*)d_in[6];
    const float* gamma  = (const float*)d_in[7];
    float* out = (float*)d_out;

    const int N = in_sizes[1];          // number of windows (32768)

    hipMemsetAsync(d_out, 0, (size_t)out_size * sizeof(float), stream);  // 0xAA-poisoned
    holtwinter_kernel<<<N / 64, 64, 0, stream>>>(
        x, y, init_L, init_b, init_S, alpha, beta, gamma, out);
}